// Round 1
// 1480.520 us; speedup vs baseline: 1.1125x; 1.1125x over previous
//
#include <hip/hip_runtime.h>
#include <hip/hip_bf16.h>
#include <math.h>
#include <stdint.h>

#define BB 16
#define CC 256
#define C4 64
#define HH 96
#define WW 96
#define HW 9216
#define EPSF 1e-5f

using bf16x8 = __attribute__((ext_vector_type(8))) short;
using bf16x4 = __attribute__((ext_vector_type(4))) short;
using f32x4  = __attribute__((ext_vector_type(4))) float;

#define GLD16(g, l) \
    __builtin_amdgcn_global_load_lds((const __attribute__((address_space(1))) unsigned int*)(g), \
                                     (__attribute__((address_space(3))) unsigned int*)(l), 16, 0, 0)

__device__ inline float bf2f_bits(short s) {
    return __uint_as_float(((unsigned int)(unsigned short)s) << 16);
}
__device__ inline short f2bf_bits(float f) {
    unsigned int u = __float_as_uint(f);
    return (short)((u + 0x7fffu + ((u >> 16) & 1u)) >> 16);
}

// ---------------- tiny zero-page init ----------------
__global__ void zero_kernel(unsigned int* __restrict__ p) { p[threadIdx.x] = 0u; }

// ---------------- per-channel mean + inv_std (var uses n-1) ----------------
__global__ void channel_stats_kernel(const float* __restrict__ x,
                                     float* __restrict__ mean_out,
                                     float* __restrict__ istd_out) {
    int bc = blockIdx.x;
    const float* p = x + (size_t)bc * HW;
    float s = 0.f, ss = 0.f;
    for (int i = threadIdx.x; i < HW; i += 256) { float v = p[i]; s += v; ss += v * v; }
    __shared__ float red[256], red2[256];
    red[threadIdx.x] = s; red2[threadIdx.x] = ss;
    __syncthreads();
    for (int off = 128; off > 0; off >>= 1) {
        if (threadIdx.x < off) { red[threadIdx.x] += red[threadIdx.x + off]; red2[threadIdx.x] += red2[threadIdx.x + off]; }
        __syncthreads();
    }
    if (threadIdx.x == 0) {
        float sum = red[0], sumsq = red2[0];
        float m = sum / (float)HW;
        float var = (sumsq - sum * m) / (float)(HW - 1);
        mean_out[bc] = m;
        istd_out[bc] = rsqrtf(var + EPSF);
    }
}

// ---------------- router softmax + freq-weight softmax ----------------
__global__ void router_kernel(const float* __restrict__ pooled, const float* __restrict__ rw,
                              const float* __restrict__ rb, const float* __restrict__ fwts,
                              float* __restrict__ route, float* __restrict__ fw) {
    int t = threadIdx.x;
    if (t < BB) {
        float l0 = rb[0], l1 = rb[1];
        for (int c = 0; c < CC; ++c) {
            float p = pooled[t * CC + c];
            l0 += p * rw[c];
            l1 += p * rw[CC + c];
        }
        float m = fmaxf(l0, l1);
        float e0 = __expf(l0 - m), e1 = __expf(l1 - m);
        float inv = 1.f / (e0 + e1);
        route[t * 2 + 0] = e0 * inv;
        route[t * 2 + 1] = e1 * inv;
    }
    if (t == BB) {
        float a = fwts[0], b = fwts[1], c = fwts[2];
        float m = fmaxf(a, fmaxf(b, c));
        float e0 = __expf(a - m), e1 = __expf(b - m), e2 = __expf(c - m);
        float inv = 1.f / (e0 + e1 + e2);
        fw[0] = e0 * inv; fw[1] = e1 * inv; fw[2] = e2 * inv;
    }
}

// ---------------- weight prep ----------------
__global__ void pack_w3x3_kernel(const float* __restrict__ w, __hip_bfloat16* __restrict__ wt,
                                 int COUT, int CINW) {
    int idx = blockIdx.x * 256 + threadIdx.x;
    int total = COUT * 9 * CINW;
    if (idx >= total) return;
    int ci = idx % CINW; int rest = idx / CINW; int tau = rest % 9; int co = rest / 9;
    wt[idx] = __float2bfloat16(w[((size_t)co * CINW + ci) * 9 + tau]);
}

__global__ void cast_w_kernel(const float* __restrict__ w, __hip_bfloat16* __restrict__ o, int n) {
    int idx = blockIdx.x * 256 + threadIdx.x;
    if (idx < n) o[idx] = __float2bfloat16(w[idx]);
}

// pww (3,256,64) + fw -> wtf (256,192) scaled; fbias[co] = sum fw[i]*pwb[i][co]
__global__ void fuse_freq_w_kernel(const float* __restrict__ pww, const float* __restrict__ pwb,
                                   const float* __restrict__ fw, __hip_bfloat16* __restrict__ wtf,
                                   float* __restrict__ fbias) {
    int co = blockIdx.x; int t = threadIdx.x;  // 192 threads
    int i = t >> 6, g = t & 63;
    wtf[co * 192 + t] = __float2bfloat16(fw[i] * pww[((size_t)(i * 256 + co)) * 64 + g]);
    if (t == 0) fbias[co] = fw[0] * pwb[co] + fw[1] * pwb[256 + co] + fw[2] * pwb[512 + co];
}

// ---------------- planar (B,CIN,HW) -> pixel-major (B,HW,CIN) bf16 ----------------
__device__ inline float to_f32(float v) { return v; }
__device__ inline float to_f32(__hip_bfloat16 v) { return __bfloat162float(v); }

template <typename TIN, int CIN>
__global__ __launch_bounds__(256) void transpose_pm_kernel(const TIN* __restrict__ x,
                                                           __hip_bfloat16* __restrict__ xt) {
    __shared__ float s[32][33];
    int p0 = blockIdx.x * 32, c0 = blockIdx.y * 32, b = blockIdx.z;
    int tx = threadIdx.x, ty = threadIdx.y;  // (32,8)
    const TIN* xp = x + ((size_t)b * CIN + c0) * HW + p0;
#pragma unroll
    for (int i = 0; i < 4; ++i) {
        int c = ty * 4 + i;
        s[c][tx] = to_f32(xp[(size_t)c * HW + tx]);
    }
    __syncthreads();
    __hip_bfloat16* yp = xt + ((size_t)b * HW + p0) * CIN + c0;
#pragma unroll
    for (int i = 0; i < 4; ++i) {
        int r = ty * 4 + i;
        yp[(size_t)r * CIN + tx] = __float2bfloat16(s[tx][r]);
    }
}

// ---------------- MFMA implicit-GEMM conv ----------------
// A: [CO_TOT][TSH*KC] bf16 weights; Bx: [.][9216][CDIM] bf16 pixel-major
// EPI: 0=f32 planar store, 1=bf16 planar store, 2=f32 planar += route[b]*val
template <int BM, int BN, int TSH, int KC, int CDIM, int EPI, int CO_TOT>
__global__ __launch_bounds__(256) void mfma_gemm_kernel(const short* __restrict__ A,
                                                        const short* __restrict__ Bx,
                                                        const short* __restrict__ zp,
                                                        const float* __restrict__ bias,
                                                        const float* __restrict__ route,
                                                        void* __restrict__ Y,
                                                        int bin0, int bout0) {
    constexpr int WM = BM / 2, WN = BN / 2;
    constexpr int FM = WM / 16, FN = WN / 16;
    constexpr int KB = KC / 32;
    constexpr int NA = BM / 16;
    constexpr int NB = BN / 16;
    __shared__ __align__(16) short As[BM * 32];
    __shared__ __align__(16) short Bs[BN * 32];
    int tid = threadIdx.x;
    int wid = tid >> 6, lane = tid & 63;
    int wy = wid >> 1, wx = wid & 1;
    int lane16 = lane & 15, quad = lane >> 4;
    int lrow = lane >> 2, lchk = lane & 3;
    int co0 = blockIdx.x * BM;
    int n0 = blockIdx.y * BN;
    int bin = blockIdx.z + bin0;
    int bout = blockIdx.z + bout0;

    f32x4 acc[FM][FN];
#pragma unroll
    for (int i = 0; i < FM; ++i)
#pragma unroll
        for (int j = 0; j < FN; ++j) acc[i][j] = (f32x4){0.f, 0.f, 0.f, 0.f};

    const short* Bbase = Bx + (size_t)bin * HW * CDIM;

    for (int tau = 0; tau < TSH; ++tau) {
        int dh = tau / 3, dw = tau % 3;
        int off = (TSH > 1) ? (dh - 1) * 96 + (dw - 1) : 0;
        for (int kb = 0; kb < KB; ++kb) {
            int kc0 = kb * 32;
#pragma unroll
            for (int t = 0; t < NA / 4; ++t) {
                int inst = wid * (NA / 4) + t;
                int row = inst * 16 + lrow;
                const short* g = A + (size_t)(co0 + row) * (TSH * KC) + tau * KC + kc0 + lchk * 8;
                GLD16(g, &As[inst * 512]);
            }
#pragma unroll
            for (int t = 0; t < NB / 4; ++t) {
                int inst = wid * (NB / 4) + t;
                int row = inst * 16 + lrow;
                int n = n0 + row;
                const short* g;
                if (TSH > 1) {
                    int h = n / 96, w = n - h * 96;
                    int hh = h + dh - 1, ww2 = w + dw - 1;
                    bool valid = ((unsigned)hh < 96u) && ((unsigned)ww2 < 96u);
                    g = valid ? (Bbase + (size_t)(n + off) * CDIM + kc0 + lchk * 8) : zp;
                } else {
                    g = Bbase + (size_t)n * CDIM + kc0 + lchk * 8;
                }
                GLD16(g, &Bs[inst * 512]);
            }
            __syncthreads();
            bf16x8 af[FM], bfr[FN];
#pragma unroll
            for (int i = 0; i < FM; ++i)
                af[i] = *(const bf16x8*)&As[(wy * WM + i * 16 + lane16) * 32 + quad * 8];
#pragma unroll
            for (int j = 0; j < FN; ++j)
                bfr[j] = *(const bf16x8*)&Bs[(wx * WN + j * 16 + lane16) * 32 + quad * 8];
#pragma unroll
            for (int i = 0; i < FM; ++i)
#pragma unroll
                for (int j = 0; j < FN; ++j)
                    acc[i][j] = __builtin_amdgcn_mfma_f32_16x16x32_bf16(af[i], bfr[j], acc[i][j], 0, 0, 0);
            __syncthreads();
        }
    }
    float scale = 1.f;
    if (EPI == 2) scale = route[bin * 2 + 1];
#pragma unroll
    for (int i = 0; i < FM; ++i) {
        int co_l = co0 + wy * WM + i * 16 + quad * 4;
#pragma unroll
        for (int j = 0; j < FN; ++j) {
            int pix = n0 + wx * WN + j * 16 + lane16;
#pragma unroll
            for (int r = 0; r < 4; ++r) {
                int co = co_l + r;
                float v = acc[i][j][r] + bias[co];
                size_t idx = ((size_t)(bout * CO_TOT + co)) * HW + pix;
                if (EPI == 0) ((float*)Y)[idx] = v;
                else if (EPI == 1) ((__hip_bfloat16*)Y)[idx] = __float2bfloat16(v);
                else ((float*)Y)[idx] += scale * v;
            }
        }
    }
}

// ---------------- AFN tiny MLP ----------------
template <int CH, int HID>
__global__ void afn_mlp_kernel(const float* __restrict__ mean,
                               const float* __restrict__ s1w, const float* __restrict__ s1b,
                               const float* __restrict__ s2w, const float* __restrict__ s2b,
                               float* __restrict__ ag, float* __restrict__ ab) {
    int b = blockIdx.x;
    __shared__ float hbuf[HID];
    int t = threadIdx.x;
    if (t < HID) {
        float s = s1b[t];
        for (int c = 0; c < CH; ++c) s += mean[b * CH + c] * s1w[t * CH + c];
        hbuf[t] = fmaxf(s, 0.f);
    }
    __syncthreads();
    if (t < 2 * CH) {
        float s = s2b[t];
#pragma unroll
        for (int k = 0; k < HID; ++k) s += hbuf[k] * s2w[t * HID + k];
        if (t < CH) ag[b * CH + t] = s;
        else        ab[b * CH + (t - CH)] = s;
    }
}

// ---------------- AFN apply (+ optional exact GELU), in place ----------------
template <int CH, bool GELU>
__global__ void afn_apply_kernel(float* __restrict__ hbuf_g, const float* __restrict__ mean,
                                 const float* __restrict__ istd, const float* __restrict__ ag,
                                 const float* __restrict__ ab, const float* __restrict__ gamma,
                                 const float* __restrict__ beta) {
    int p = blockIdx.x * 256 + threadIdx.x;
    int c = blockIdx.y, b = blockIdx.z;
    int bc = b * CH + c;
    float scale = (1.f + ag[bc]) * gamma[c] * istd[bc];
    float shift = ab[bc] * beta[c];
    float m = mean[bc];
    float* ptr = hbuf_g + (size_t)bc * HW + p;
    float v = (*ptr - m) * scale + shift;
    if (GELU) v = 0.5f * v * (1.f + erff(v * 0.70710678118654752f));
    *ptr = v;
}

// ---------------- out = x + route0 * out1 ----------------
__global__ void combine_kernel(const float* __restrict__ x, const float* __restrict__ out1,
                               const float* __restrict__ route, float* __restrict__ out) {
    int b = blockIdx.y;
    size_t i = (size_t)b * CC * HW + (size_t)blockIdx.x * 256 + threadIdx.x;
    float r0 = route[b * 2];
    out[i] = x[i] + r0 * out1[i];
}

// ---------------- spatial transpose of V channels: [g][w] -> [w][g] bf16 ----------------
__global__ __launch_bounds__(256) void vtrans_kernel(const __hip_bfloat16* __restrict__ qkv,
                                                     __hip_bfloat16* __restrict__ vt) {
    __shared__ __hip_bfloat16 s[32][34];
    int th = blockIdx.x / 3, tw = blockIdx.x % 3;   // 3x3 tiles of 32
    int c = blockIdx.y, b = blockIdx.z;
    int tx = threadIdx.x, ty = threadIdx.y;  // (32,8)
    const __hip_bfloat16* ip = qkv + ((size_t)b * 768 + 512 + c) * HW + (size_t)(th * 32) * 96 + tw * 32;
#pragma unroll
    for (int i = 0; i < 4; ++i) s[ty * 4 + i][tx] = ip[(size_t)(ty * 4 + i) * 96 + tx];
    __syncthreads();
    __hip_bfloat16* op = vt + ((size_t)b * 256 + c) * HW + (size_t)(tw * 32) * 96 + th * 32;
#pragma unroll
    for (int i = 0; i < 4; ++i) op[(size_t)(ty * 4 + i) * 96 + tx] = s[tx][ty * 4 + i];
}

// ---------------- MFMA attention: one block per (d, n, b_local) ----------------
// Q,K row-major [h|g][w] from qkv; V^T row-major [w][g] from vt.
// 4 waves, each owns a 48x48 quadrant of the 96x96 output; K=96 in 3 chunks of 32.
// Only P (scores/probs) is staged in LDS (96 rows, padded to 104 bf16 to kill
// the stride-192B bank conflict on ds_read_b128 fragment loads).
__global__ __launch_bounds__(256) void attn_mfma_kernel(const __hip_bfloat16* __restrict__ qkv,
                                                        const __hip_bfloat16* __restrict__ vt,
                                                        __hip_bfloat16* __restrict__ a, int bout0) {
    int d = blockIdx.x, n = blockIdx.y, b = blockIdx.z;
    __shared__ __align__(16) __hip_bfloat16 Ps[96 * 104];
    int t = threadIdx.x;
    int lane = t & 63, wid = t >> 6;
    int wy = wid >> 1, wx = wid & 1;
    int lane16 = lane & 15, quad = lane >> 4;

    const __hip_bfloat16* qp = qkv + ((size_t)b * 768 + n * 32 + d) * HW;
    const __hip_bfloat16* kp = qp + (size_t)256 * HW;
    const __hip_bfloat16* vp = vt + ((size_t)b * 256 + n * 32 + d) * HW;

    f32x4 acc[3][3];
#pragma unroll
    for (int i = 0; i < 3; ++i)
#pragma unroll
        for (int j = 0; j < 3; ++j) acc[i][j] = (f32x4){0.f, 0.f, 0.f, 0.f};

    // ---- QK^T: D[h,g] = sum_w Q[h,w] K[g,w], operands direct from global ----
#pragma unroll
    for (int kb = 0; kb < 3; ++kb) {
        int kc = kb * 32 + quad * 8;
        bf16x8 af[3], bfr[3];
#pragma unroll
        for (int i = 0; i < 3; ++i)
            af[i] = *(const bf16x8*)(qp + (size_t)(wy * 48 + i * 16 + lane16) * 96 + kc);
#pragma unroll
        for (int j = 0; j < 3; ++j)
            bfr[j] = *(const bf16x8*)(kp + (size_t)(wx * 48 + j * 16 + lane16) * 96 + kc);
#pragma unroll
        for (int i = 0; i < 3; ++i)
#pragma unroll
            for (int j = 0; j < 3; ++j)
                acc[i][j] = __builtin_amdgcn_mfma_f32_16x16x32_bf16(af[i], bfr[j], acc[i][j], 0, 0, 0);
    }

    // ---- scaled scores -> LDS (C layout: col=lane16, row=quad*4+r) ----
    const float scale = 0.0625f;  // 256^-0.5
#pragma unroll
    for (int i = 0; i < 3; ++i) {
        int rbase = wy * 48 + i * 16 + quad * 4;
#pragma unroll
        for (int j = 0; j < 3; ++j) {
            int col = wx * 48 + j * 16 + lane16;
#pragma unroll
            for (int r = 0; r < 4; ++r)
                Ps[(rbase + r) * 104 + col] = __float2bfloat16(acc[i][j][r] * scale);
        }
    }
    __syncthreads();

    // ---- row softmax: 2 threads per row, 48 cols each, shfl_xor(1) combine ----
    if (t < 192) {
        int row = t >> 1, hh = t & 1;
        const bf16x4* pr4 = (const bf16x4*)&Ps[row * 104 + hh * 48];
        float vb[48];
        float m = -1e30f;
#pragma unroll
        for (int j4 = 0; j4 < 12; ++j4) {
            bf16x4 u = pr4[j4];
#pragma unroll
            for (int e = 0; e < 4; ++e) {
                float f = bf2f_bits(u[e]);
                vb[j4 * 4 + e] = f;
                m = fmaxf(m, f);
            }
        }
        m = fmaxf(m, __shfl_xor(m, 1));
        float ssum = 0.f;
#pragma unroll
        for (int j2 = 0; j2 < 48; ++j2) { vb[j2] = __expf(vb[j2] - m); ssum += vb[j2]; }
        ssum += __shfl_xor(ssum, 1);
        float inv = 1.f / ssum;
        bf16x4* pw4 = (bf16x4*)&Ps[row * 104 + hh * 48];
#pragma unroll
        for (int j4 = 0; j4 < 12; ++j4) {
            bf16x4 o;
#pragma unroll
            for (int e = 0; e < 4; ++e) o[e] = f2bf_bits(vb[j4 * 4 + e] * inv);
            pw4[j4] = o;
        }
    }
    __syncthreads();

    // ---- PV: D[h,w] = sum_g P[h,g] V^T[w,g] ----
#pragma unroll
    for (int i = 0; i < 3; ++i)
#pragma unroll
        for (int j = 0; j < 3; ++j) acc[i][j] = (f32x4){0.f, 0.f, 0.f, 0.f};

#pragma unroll
    for (int kb = 0; kb < 3; ++kb) {
        int kc = kb * 32 + quad * 8;
        bf16x8 af[3], bfr[3];
#pragma unroll
        for (int i = 0; i < 3; ++i)
            af[i] = *(const bf16x8*)&Ps[(wy * 48 + i * 16 + lane16) * 104 + kc];
#pragma unroll
        for (int j = 0; j < 3; ++j)
            bfr[j] = *(const bf16x8*)(vp + (size_t)(wx * 48 + j * 16 + lane16) * 96 + kc);
#pragma unroll
        for (int i = 0; i < 3; ++i)
#pragma unroll
            for (int j = 0; j < 3; ++j)
                acc[i][j] = __builtin_amdgcn_mfma_f32_16x16x32_bf16(af[i], bfr[j], acc[i][j], 0, 0, 0);
    }

    // ---- store planar bf16 ----
    __hip_bfloat16* ap = a + ((size_t)(bout0 + b) * CC + (d * 8 + n)) * HW;
#pragma unroll
    for (int i = 0; i < 3; ++i) {
        int rbase = wy * 48 + i * 16 + quad * 4;
#pragma unroll
        for (int j = 0; j < 3; ++j) {
            int col = wx * 48 + j * 16 + lane16;
#pragma unroll
            for (int r = 0; r < 4; ++r)
                ap[(size_t)(rbase + r) * 96 + col] = __float2bfloat16(acc[i][j][r]);
        }
    }
}

// ---------------- grouped 3x3 conv + exact GELU -> bf16 planar ----------------
__global__ __launch_bounds__(256) void freqdw_kernel(const float* __restrict__ x,
                                                     const float* __restrict__ wgt,
                                                     const float* __restrict__ bias,
                                                     __hip_bfloat16* __restrict__ f, int cbase) {
    int p = blockIdx.x * 256 + threadIdx.x;
    int g = blockIdx.y;
    int b = blockIdx.z;
    int h = p / WW, w = p % WW;
    float acc = bias[g];
    const float* wq = wgt + g * 36;
#pragma unroll
    for (int q = 0; q < 4; ++q) {
        const float* xc = x + ((size_t)b * CC + 4 * g + q) * HW;
#pragma unroll
        for (int dh = 0; dh < 3; ++dh) {
            int hh = h + dh - 1;
            bool hv = (hh >= 0) && (hh < HH);
#pragma unroll
            for (int dw = 0; dw < 3; ++dw) {
                int ww2 = w + dw - 1;
                bool v = hv && (ww2 >= 0) && (ww2 < WW);
                float xv = v ? xc[hh * WW + ww2] : 0.f;
                acc += xv * wq[q * 9 + dh * 3 + dw];
            }
        }
    }
    acc = 0.5f * acc * (1.f + erff(acc * 0.70710678118654752f));
    f[((size_t)b * 192 + cbase + g) * HW + p] = __float2bfloat16(acc);
}

extern "C" void kernel_launch(void* const* d_in, const int* in_sizes, int n_in,
                              void* d_out, int out_size, void* d_ws, size_t ws_size,
                              hipStream_t stream) {
    const float* x    = (const float*)d_in[0];
    const float* c1w  = (const float*)d_in[1];
    const float* c1b  = (const float*)d_in[2];
    const float* g1   = (const float*)d_in[3];
    const float* be1  = (const float*)d_in[4];
    const float* s1w1 = (const float*)d_in[5];
    const float* s1b1 = (const float*)d_in[6];
    const float* s2w1 = (const float*)d_in[7];
    const float* s2b1 = (const float*)d_in[8];
    const float* c2w  = (const float*)d_in[9];
    const float* c2b  = (const float*)d_in[10];
    const float* g2   = (const float*)d_in[11];
    const float* be2  = (const float*)d_in[12];
    const float* s1w2 = (const float*)d_in[13];
    const float* s1b2 = (const float*)d_in[14];
    const float* s2w2 = (const float*)d_in[15];
    const float* s2b2 = (const float*)d_in[16];
    const float* qkvw = (const float*)d_in[17];
    const float* qkvb = (const float*)d_in[18];
    const float* pjw  = (const float*)d_in[19];
    const float* pjb  = (const float*)d_in[20];
    const float* dww  = (const float*)d_in[21];
    const float* dwb  = (const float*)d_in[22];
    const float* pww  = (const float*)d_in[23];
    const float* pwb  = (const float*)d_in[24];
    const float* fwts = (const float*)d_in[25];
    const float* rw   = (const float*)d_in[26];
    const float* rb   = (const float*)d_in[27];
    float* out = (float*)d_out;
    (void)ws_size;

    char* ws = (char*)d_ws;
    // ---- workspace map (peak ~284.4 MB; round-1 proved >=302.1 MB is safe) ----
    // [0,151.0M): h2 f32 (phase1); later qkvs bf16 (8 batches, 113.25M) / at_t / fall / f_t
    float* h2 = (float*)ws;
    __hip_bfloat16* qkvs = (__hip_bfloat16*)ws;                      // 113,246,208 B
    __hip_bfloat16* at_t = (__hip_bfloat16*)ws;                      //  75,497,472 B
    __hip_bfloat16* fall = (__hip_bfloat16*)ws;                      //  56,623,104 B
    __hip_bfloat16* f_t  = (__hip_bfloat16*)(ws + 56623104ULL);      //  56,623,104 B
    // [113.25M, 151.0M): vt bf16 (8 batches, spatial-transposed V) during attn phase
    __hip_bfloat16* vt = (__hip_bfloat16*)(ws + 113246208ULL);       //  37,748,736 B
    // [151.0M, 188.7M): h1 f32 (dead by attention phase)
    float* h1 = (float*)(ws + 150994944ULL);
    // [188.7M, 207.6M): h1t bf16
    __hip_bfloat16* h1t = (__hip_bfloat16*)(ws + 188743680ULL);
    // [207.6M, 283.1M): xt bf16 (B,HW,256); per-half overwritten by at (planar bf16)
    __hip_bfloat16* xt = (__hip_bfloat16*)(ws + 207618048ULL);
    __hip_bfloat16* at = xt;
    // tail [283.1M, ~284.4M): zero page + stats + bf16 weights
    const size_t TB = 283115520ULL;
    short* zp = (short*)(ws + TB);            // 256 B
    float* stats = (float*)(ws + TB + 256);
    float* pooled_x = stats;                  // 4096
    float* route    = pooled_x + 4096;        // 32
    float* fw       = route + 32;             // 4
    float* mean1    = fw + 4;                 // 1024
    float* istd1    = mean1 + 1024;
    float* ag1      = istd1 + 1024;
    float* ab1      = ag1 + 1024;
    float* mean2    = ab1 + 1024;             // 4096
    float* istd2    = mean2 + 4096;
    float* ag2      = istd2 + 4096;
    float* ab2      = ag2 + 4096;
    float* fbias    = ab2 + 4096;             // 256
    float* dummy    = fbias + 256;            // 4096
    char* wbase = (char*)(dummy + 4096);
    __hip_bfloat16* wt1  = (__hip_bfloat16*)wbase;              // 64*9*256
    __hip_bfloat16* wt2  = (__hip_bfloat16*)(wbase + 294912);   // 256*9*64
    __hip_bfloat16* qw16 = (__hip_bfloat16*)(wbase + 589824);   // 768*256
    __hip_bfloat16* pw16 = (__hip_bfloat16*)(wbase + 983040);   // 256*256
    __hip_bfloat16* wtf  = (__hip_bfloat16*)(wbase + 1114112);  // 256*192

    zero_kernel<<<1, 64, 0, stream>>>((unsigned int*)zp);

    // stats + routing
    channel_stats_kernel<<<dim3(BB * CC), 256, 0, stream>>>(x, pooled_x, dummy);
    router_kernel<<<1, 64, 0, stream>>>(pooled_x, rw, rb, fwts, route, fw);

    // weight prep
    pack_w3x3_kernel<<<576, 256, 0, stream>>>(c1w, wt1, 64, 256);
    pack_w3x3_kernel<<<576, 256, 0, stream>>>(c2w, wt2, 256, 64);
    cast_w_kernel<<<768, 256, 0, stream>>>(qkvw, qw16, 768 * 256);
    cast_w_kernel<<<256, 256, 0, stream>>>(pjw, pw16, 256 * 256);
    fuse_freq_w_kernel<<<256, 192, 0, stream>>>(pww, pwb, fw, wtf, fbias);

    // x -> pixel-major bf16
    transpose_pm_kernel<float, 256><<<dim3(288, 8, 16), dim3(32, 8), 0, stream>>>(x, xt);

    // branch 1: conv1 -> AFN1+GELU -> conv2 -> AFN2
    mfma_gemm_kernel<64, 128, 9, 256, 256, 0, 64>
        <<<dim3(1, 72, 16), 256, 0, stream>>>((const short*)wt1, (const short*)xt, zp, c1b, nullptr, h1, 0, 0);
    channel_stats_kernel<<<dim3(BB * C4), 256, 0, stream>>>(h1, mean1, istd1);
    afn_mlp_kernel<64, 16><<<dim3(BB), 128, 0, stream>>>(mean1, s1w1, s1b1, s2w1, s2b1, ag1, ab1);
    afn_apply_kernel<64, true><<<dim3(36, 64, 16), 256, 0, stream>>>(h1, mean1, istd1, ag1, ab1, g1, be1);
    transpose_pm_kernel<float, 64><<<dim3(288, 2, 16), dim3(32, 8), 0, stream>>>(h1, h1t);
    mfma_gemm_kernel<128, 128, 9, 64, 64, 0, 256>
        <<<dim3(2, 72, 16), 256, 0, stream>>>((const short*)wt2, (const short*)h1t, zp, c2b, nullptr, h2, 0, 0);
    channel_stats_kernel<<<dim3(BB * CC), 256, 0, stream>>>(h2, mean2, istd2);
    afn_mlp_kernel<256, 64><<<dim3(BB), 512, 0, stream>>>(mean2, s1w2, s1b2, s2w2, s2b2, ag2, ab2);
    afn_apply_kernel<256, false><<<dim3(36, 256, 16), 256, 0, stream>>>(h2, mean2, istd2, ag2, ab2, g2, be2);

    // out = x + r0*out1  (h2 dead afterwards -> region reused for qkvs)
    combine_kernel<<<dim3(9216, 16), 256, 0, stream>>>(x, h2, route, out);

    // attention branch, two batch-halves sharing the qkv scratch
    for (int half = 0; half < 2; ++half) {
        mfma_gemm_kernel<128, 128, 1, 256, 256, 1, 768>
            <<<dim3(6, 72, 8), 256, 0, stream>>>((const short*)qw16, (const short*)xt, zp, qkvb,
                                                 nullptr, qkvs, half * 8, 0);
        vtrans_kernel<<<dim3(9, 256, 8), dim3(32, 8), 0, stream>>>(qkvs, vt);
        attn_mfma_kernel<<<dim3(32, 8, 8), 256, 0, stream>>>(qkvs, vt, at, half * 8);
    }
    transpose_pm_kernel<__hip_bfloat16, 256><<<dim3(288, 8, 16), dim3(32, 8), 0, stream>>>(at, at_t);
    mfma_gemm_kernel<128, 128, 1, 256, 256, 2, 256>
        <<<dim3(2, 72, 16), 256, 0, stream>>>((const short*)pw16, (const short*)at_t, zp, pjb, route, out, 0, 0);

    // frequency branches: 3 dw convs -> fall (B,192,HW) bf16, one fused GEMM
    for (int i = 0; i < 3; ++i)
        freqdw_kernel<<<dim3(36, 64, 16), 256, 0, stream>>>(x, dww + i * C4 * 36, dwb + i * C4, fall, i * 64);
    transpose_pm_kernel<__hip_bfloat16, 192><<<dim3(288, 6, 16), dim3(32, 8), 0, stream>>>(fall, f_t);
    mfma_gemm_kernel<128, 128, 1, 192, 192, 2, 256>
        <<<dim3(2, 72, 16), 256, 0, stream>>>((const short*)wtf, (const short*)f_t, zp, fbias, route, out, 0, 0);
}

// Round 2
// 1224.337 us; speedup vs baseline: 1.3453x; 1.2092x over previous
//
#include <hip/hip_runtime.h>
#include <hip/hip_bf16.h>
#include <math.h>
#include <stdint.h>

#define BB 16
#define CC 256
#define C4 64
#define HH 96
#define WW 96
#define HW 9216
#define EPSF 1e-5f

using bf16x8 = __attribute__((ext_vector_type(8))) short;
using bf16x4 = __attribute__((ext_vector_type(4))) short;
using f32x4  = __attribute__((ext_vector_type(4))) float;

#define GLD16(g, l) \
    __builtin_amdgcn_global_load_lds((const __attribute__((address_space(1))) unsigned int*)(g), \
                                     (__attribute__((address_space(3))) unsigned int*)(l), 16, 0, 0)

__device__ inline float bf2f_bits(short s) {
    return __uint_as_float(((unsigned int)(unsigned short)s) << 16);
}
__device__ inline short f2bf_bits(float f) {
    unsigned int u = __float_as_uint(f);
    return (short)((u + 0x7fffu + ((u >> 16) & 1u)) >> 16);
}

// ---------------- zero init for zp + stat accumulators ----------------
__global__ void zero_n_kernel(unsigned int* __restrict__ p, int n) {
    int i = blockIdx.x * 256 + threadIdx.x;
    if (i < n) p[i] = 0u;
}

// ---------------- router softmax + freq-weight softmax (pooled holds SUMS) ----------------
__global__ void router_kernel(const float* __restrict__ pooled, const float* __restrict__ rw,
                              const float* __restrict__ rb, const float* __restrict__ fwts,
                              float* __restrict__ route, float* __restrict__ fw) {
    int t = threadIdx.x;
    const float invhw = 1.f / (float)HW;
    if (t < BB) {
        float l0 = rb[0], l1 = rb[1];
        for (int c = 0; c < CC; ++c) {
            float p = pooled[t * CC + c] * invhw;
            l0 += p * rw[c];
            l1 += p * rw[CC + c];
        }
        float m = fmaxf(l0, l1);
        float e0 = __expf(l0 - m), e1 = __expf(l1 - m);
        float inv = 1.f / (e0 + e1);
        route[t * 2 + 0] = e0 * inv;
        route[t * 2 + 1] = e1 * inv;
    }
    if (t == BB) {
        float a = fwts[0], b = fwts[1], c = fwts[2];
        float m = fmaxf(a, fmaxf(b, c));
        float e0 = __expf(a - m), e1 = __expf(b - m), e2 = __expf(c - m);
        float inv = 1.f / (e0 + e1 + e2);
        fw[0] = e0 * inv; fw[1] = e1 * inv; fw[2] = e2 * inv;
    }
}

// ---------------- weight prep ----------------
__global__ void pack_w3x3_kernel(const float* __restrict__ w, __hip_bfloat16* __restrict__ wt,
                                 int COUT, int CINW) {
    int idx = blockIdx.x * 256 + threadIdx.x;
    int total = COUT * 9 * CINW;
    if (idx >= total) return;
    int ci = idx % CINW; int rest = idx / CINW; int tau = rest % 9; int co = rest / 9;
    wt[idx] = __float2bfloat16(w[((size_t)co * CINW + ci) * 9 + tau]);
}

__global__ void cast_w_kernel(const float* __restrict__ w, __hip_bfloat16* __restrict__ o, int n) {
    int idx = blockIdx.x * 256 + threadIdx.x;
    if (idx < n) o[idx] = __float2bfloat16(w[idx]);
}

// proj weights (256,256) -> A448 rows [0:256), stride 448
__global__ void cast_w448_kernel(const float* __restrict__ w, __hip_bfloat16* __restrict__ A448) {
    int idx = blockIdx.x * 256 + threadIdx.x;  // 65536
    int co = idx >> 8, ci = idx & 255;
    A448[co * 448 + ci] = __float2bfloat16(w[idx]);
}

// pww (3,256,64)*fw -> A448 cols [256:448); fb448[co] = pjb[co] + sum fw[i]*pwb[i][co]
__global__ void fuse_freq_w448_kernel(const float* __restrict__ pww, const float* __restrict__ pwb,
                                      const float* __restrict__ pjb, const float* __restrict__ fw,
                                      __hip_bfloat16* __restrict__ A448, float* __restrict__ fb448) {
    int co = blockIdx.x; int t = threadIdx.x;  // 192 threads
    int i = t >> 6, g = t & 63;
    A448[co * 448 + 256 + t] = __float2bfloat16(fw[i] * pww[((size_t)(i * 256 + co)) * 64 + g]);
    if (t == 0) fb448[co] = pjb[co] + fw[0] * pwb[co] + fw[1] * pwb[256 + co] + fw[2] * pwb[512 + co];
}

// ---------------- planar (B,CIN,HW) -> pixel-major (B,HW,OSTR) bf16 ----------------
__device__ inline float to_f32(float v) { return v; }
__device__ inline float to_f32(__hip_bfloat16 v) { return __bfloat162float(v); }

template <typename TIN, int CIN, int OSTR, bool POOL>
__global__ __launch_bounds__(256) void transpose_pm_kernel(const TIN* __restrict__ x,
                                                           __hip_bfloat16* __restrict__ xt,
                                                           float* __restrict__ pooled) {
    __shared__ float s[32][33];
    __shared__ float ps[8][32];
    int p0 = blockIdx.x * 32, c0 = blockIdx.y * 32, b = blockIdx.z;
    int tx = threadIdx.x, ty = threadIdx.y;  // (32,8)
    const TIN* xp = x + ((size_t)b * CIN + c0) * HW + p0;
#pragma unroll
    for (int i = 0; i < 4; ++i) {
        int c = ty * 4 + i;
        s[c][tx] = to_f32(xp[(size_t)c * HW + tx]);
    }
    __syncthreads();
    __hip_bfloat16* yp = xt + ((size_t)b * HW + p0) * OSTR + c0;
#pragma unroll
    for (int i = 0; i < 4; ++i) {
        int r = ty * 4 + i;
        yp[(size_t)r * OSTR + tx] = __float2bfloat16(s[tx][r]);
    }
    if (POOL) {
        // channel c0+tx: partial sum over this block's 32 pixels
        float l4 = 0.f;
#pragma unroll
        for (int i = 0; i < 4; ++i) l4 += s[tx][ty * 4 + i];
        ps[ty][tx] = l4;
        __syncthreads();
        if (ty == 0) {
            float tot = 0.f;
#pragma unroll
            for (int k = 0; k < 8; ++k) tot += ps[k][tx];
            atomicAdd(&pooled[b * CIN + c0 + tx], tot);
        }
    }
}

// ---------------- MFMA implicit-GEMM conv ----------------
// A: [CO_TOT][TSH*KC] bf16 weights; Bx: [.][9216][CDIM] bf16 pixel-major
// EPI: 0=f32 planar store, 1=bf16 planar store, 2=f32 planar += route[b]*val
// STATS: accumulate per-(b,co) sum / sumsq via atomics (for fused channel stats)
template <int BM, int BN, int TSH, int KC, int CDIM, int EPI, int CO_TOT, bool STATS>
__global__ __launch_bounds__(256) void mfma_gemm_kernel(const short* __restrict__ A,
                                                        const short* __restrict__ Bx,
                                                        const short* __restrict__ zp,
                                                        const float* __restrict__ bias,
                                                        const float* __restrict__ route,
                                                        void* __restrict__ Y,
                                                        float* __restrict__ ssum,
                                                        float* __restrict__ sssq,
                                                        int bin0, int bout0) {
    constexpr int WM = BM / 2, WN = BN / 2;
    constexpr int FM = WM / 16, FN = WN / 16;
    constexpr int KB = KC / 32;
    constexpr int NA = BM / 16;
    constexpr int NB = BN / 16;
    __shared__ __align__(16) short As[BM * 32];
    __shared__ __align__(16) short Bs[BN * 32];
    int tid = threadIdx.x;
    int wid = tid >> 6, lane = tid & 63;
    int wy = wid >> 1, wx = wid & 1;
    int lane16 = lane & 15, quad = lane >> 4;
    int lrow = lane >> 2, lchk = lane & 3;
    int co0 = blockIdx.x * BM;
    int n0 = blockIdx.y * BN;
    int bin = blockIdx.z + bin0;
    int bout = blockIdx.z + bout0;

    f32x4 acc[FM][FN];
#pragma unroll
    for (int i = 0; i < FM; ++i)
#pragma unroll
        for (int j = 0; j < FN; ++j) acc[i][j] = (f32x4){0.f, 0.f, 0.f, 0.f};

    const short* Bbase = Bx + (size_t)bin * HW * CDIM;

    for (int tau = 0; tau < TSH; ++tau) {
        int dh = tau / 3, dw = tau % 3;
        int off = (TSH > 1) ? (dh - 1) * 96 + (dw - 1) : 0;
        for (int kb = 0; kb < KB; ++kb) {
            int kc0 = kb * 32;
#pragma unroll
            for (int t = 0; t < NA / 4; ++t) {
                int inst = wid * (NA / 4) + t;
                int row = inst * 16 + lrow;
                const short* g = A + (size_t)(co0 + row) * (TSH * KC) + tau * KC + kc0 + lchk * 8;
                GLD16(g, &As[inst * 512]);
            }
#pragma unroll
            for (int t = 0; t < NB / 4; ++t) {
                int inst = wid * (NB / 4) + t;
                int row = inst * 16 + lrow;
                int n = n0 + row;
                const short* g;
                if (TSH > 1) {
                    int h = n / 96, w = n - h * 96;
                    int hh = h + dh - 1, ww2 = w + dw - 1;
                    bool valid = ((unsigned)hh < 96u) && ((unsigned)ww2 < 96u);
                    g = valid ? (Bbase + (size_t)(n + off) * CDIM + kc0 + lchk * 8) : zp;
                } else {
                    g = Bbase + (size_t)n * CDIM + kc0 + lchk * 8;
                }
                GLD16(g, &Bs[inst * 512]);
            }
            __syncthreads();
            bf16x8 af[FM], bfr[FN];
#pragma unroll
            for (int i = 0; i < FM; ++i)
                af[i] = *(const bf16x8*)&As[(wy * WM + i * 16 + lane16) * 32 + quad * 8];
#pragma unroll
            for (int j = 0; j < FN; ++j)
                bfr[j] = *(const bf16x8*)&Bs[(wx * WN + j * 16 + lane16) * 32 + quad * 8];
#pragma unroll
            for (int i = 0; i < FM; ++i)
#pragma unroll
                for (int j = 0; j < FN; ++j)
                    acc[i][j] = __builtin_amdgcn_mfma_f32_16x16x32_bf16(af[i], bfr[j], acc[i][j], 0, 0, 0);
            __syncthreads();
        }
    }
    float scale = 1.f;
    if (EPI == 2) scale = route[bin * 2 + 1];
    float sl[FM][4], ql[FM][4];
    if (STATS) {
#pragma unroll
        for (int i = 0; i < FM; ++i)
#pragma unroll
            for (int r = 0; r < 4; ++r) { sl[i][r] = 0.f; ql[i][r] = 0.f; }
    }
#pragma unroll
    for (int i = 0; i < FM; ++i) {
        int co_l = co0 + wy * WM + i * 16 + quad * 4;
#pragma unroll
        for (int j = 0; j < FN; ++j) {
            int pix = n0 + wx * WN + j * 16 + lane16;
#pragma unroll
            for (int r = 0; r < 4; ++r) {
                int co = co_l + r;
                float v = acc[i][j][r] + bias[co];
                size_t idx = ((size_t)(bout * CO_TOT + co)) * HW + pix;
                if (EPI == 0) ((float*)Y)[idx] = v;
                else if (EPI == 1) ((__hip_bfloat16*)Y)[idx] = __float2bfloat16(v);
                else ((float*)Y)[idx] += scale * v;
                if (STATS) { sl[i][r] += v; ql[i][r] += v * v; }
            }
        }
    }
    if (STATS) {
#pragma unroll
        for (int i = 0; i < FM; ++i) {
            int co_l = co0 + wy * WM + i * 16 + quad * 4;
#pragma unroll
            for (int r = 0; r < 4; ++r) {
                float s = sl[i][r], q = ql[i][r];
                s += __shfl_xor(s, 1); q += __shfl_xor(q, 1);
                s += __shfl_xor(s, 2); q += __shfl_xor(q, 2);
                s += __shfl_xor(s, 4); q += __shfl_xor(q, 4);
                s += __shfl_xor(s, 8); q += __shfl_xor(q, 8);
                if (lane16 == 0) {
                    int bc = bout * CO_TOT + co_l + r;
                    atomicAdd(&ssum[bc], s);
                    atomicAdd(&sssq[bc], q);
                }
            }
        }
    }
}

// ---------------- stats finalize: mean + inv_std (var uses n-1) ----------------
__global__ void afn_finalize_kernel(const float* __restrict__ s, const float* __restrict__ q,
                                    float* __restrict__ mean, float* __restrict__ istd, int n) {
    int i = blockIdx.x * 256 + threadIdx.x;
    if (i >= n) return;
    float m = s[i] / (float)HW;
    float var = (q[i] - s[i] * m) / (float)(HW - 1);
    mean[i] = m;
    istd[i] = rsqrtf(var + EPSF);
}

// ---------------- AFN tiny MLP ----------------
template <int CH, int HID>
__global__ void afn_mlp_kernel(const float* __restrict__ mean,
                               const float* __restrict__ s1w, const float* __restrict__ s1b,
                               const float* __restrict__ s2w, const float* __restrict__ s2b,
                               float* __restrict__ ag, float* __restrict__ ab) {
    int b = blockIdx.x;
    __shared__ float hbuf[HID];
    int t = threadIdx.x;
    if (t < HID) {
        float s = s1b[t];
        for (int c = 0; c < CH; ++c) s += mean[b * CH + c] * s1w[t * CH + c];
        hbuf[t] = fmaxf(s, 0.f);
    }
    __syncthreads();
    if (t < 2 * CH) {
        float s = s2b[t];
#pragma unroll
        for (int k = 0; k < HID; ++k) s += hbuf[k] * s2w[t * HID + k];
        if (t < CH) ag[b * CH + t] = s;
        else        ab[b * CH + (t - CH)] = s;
    }
}

// ---------------- AFN apply (+ optional exact GELU), in place ----------------
template <int CH, bool GELU>
__global__ void afn_apply_kernel(float* __restrict__ hbuf_g, const float* __restrict__ mean,
                                 const float* __restrict__ istd, const float* __restrict__ ag,
                                 const float* __restrict__ ab, const float* __restrict__ gamma,
                                 const float* __restrict__ beta) {
    int p = blockIdx.x * 256 + threadIdx.x;
    int c = blockIdx.y, b = blockIdx.z;
    int bc = b * CH + c;
    float scale = (1.f + ag[bc]) * gamma[c] * istd[bc];
    float shift = ab[bc] * beta[c];
    float m = mean[bc];
    float* ptr = hbuf_g + (size_t)bc * HW + p;
    float v = (*ptr - m) * scale + shift;
    if (GELU) v = 0.5f * v * (1.f + erff(v * 0.70710678118654752f));
    *ptr = v;
}

// ---------------- fused AFN2 + combine: out = x + r0*AFN(h2), float4 ----------------
__global__ __launch_bounds__(256) void afn_combine_kernel(const float* __restrict__ x,
                                                          const float* __restrict__ h2,
                                                          const float* __restrict__ mean,
                                                          const float* __restrict__ istd,
                                                          const float* __restrict__ ag,
                                                          const float* __restrict__ ab,
                                                          const float* __restrict__ gamma,
                                                          const float* __restrict__ beta,
                                                          const float* __restrict__ route,
                                                          float* __restrict__ out) {
    int p4 = blockIdx.x * 256 + threadIdx.x;  // float4 index within channel (9216/4 = 2304)
    int c = blockIdx.y, b = blockIdx.z;
    int bc = b * CC + c;
    float scale = (1.f + ag[bc]) * gamma[c] * istd[bc];
    float shift = ab[bc] * beta[c];
    float m = mean[bc];
    float r0 = route[b * 2];
    size_t base = (size_t)bc * (HW / 4) + p4;
    const f32x4 xv = ((const f32x4*)x)[base];
    const f32x4 hv = ((const f32x4*)h2)[base];
    f32x4 o;
#pragma unroll
    for (int e = 0; e < 4; ++e) o[e] = xv[e] + r0 * ((hv[e] - m) * scale + shift);
    ((f32x4*)out)[base] = o;
}

// ---------------- spatial transpose of V channels: [g][w] -> [w][g] bf16 ----------------
__global__ __launch_bounds__(256) void vtrans_kernel(const __hip_bfloat16* __restrict__ qkv,
                                                     __hip_bfloat16* __restrict__ vt) {
    __shared__ __hip_bfloat16 s[32][34];
    int th = blockIdx.x / 3, tw = blockIdx.x % 3;   // 3x3 tiles of 32
    int c = blockIdx.y, b = blockIdx.z;
    int tx = threadIdx.x, ty = threadIdx.y;  // (32,8)
    const __hip_bfloat16* ip = qkv + ((size_t)b * 768 + 512 + c) * HW + (size_t)(th * 32) * 96 + tw * 32;
#pragma unroll
    for (int i = 0; i < 4; ++i) s[ty * 4 + i][tx] = ip[(size_t)(ty * 4 + i) * 96 + tx];
    __syncthreads();
    __hip_bfloat16* op = vt + ((size_t)b * 256 + c) * HW + (size_t)(tw * 32) * 96 + th * 32;
#pragma unroll
    for (int i = 0; i < 4; ++i) op[(size_t)(ty * 4 + i) * 96 + tx] = s[tx][ty * 4 + i];
}

// ---------------- MFMA attention: one block per (d, n, b_local) ----------------
__global__ __launch_bounds__(256) void attn_mfma_kernel(const __hip_bfloat16* __restrict__ qkv,
                                                        const __hip_bfloat16* __restrict__ vt,
                                                        __hip_bfloat16* __restrict__ a, int bout0) {
    int d = blockIdx.x, n = blockIdx.y, b = blockIdx.z;
    __shared__ __align__(16) __hip_bfloat16 Ps[96 * 104];
    int t = threadIdx.x;
    int lane = t & 63, wid = t >> 6;
    int wy = wid >> 1, wx = wid & 1;
    int lane16 = lane & 15, quad = lane >> 4;

    const __hip_bfloat16* qp = qkv + ((size_t)b * 768 + n * 32 + d) * HW;
    const __hip_bfloat16* kp = qp + (size_t)256 * HW;
    const __hip_bfloat16* vp = vt + ((size_t)b * 256 + n * 32 + d) * HW;

    f32x4 acc[3][3];
#pragma unroll
    for (int i = 0; i < 3; ++i)
#pragma unroll
        for (int j = 0; j < 3; ++j) acc[i][j] = (f32x4){0.f, 0.f, 0.f, 0.f};

    // ---- QK^T ----
#pragma unroll
    for (int kb = 0; kb < 3; ++kb) {
        int kc = kb * 32 + quad * 8;
        bf16x8 af[3], bfr[3];
#pragma unroll
        for (int i = 0; i < 3; ++i)
            af[i] = *(const bf16x8*)(qp + (size_t)(wy * 48 + i * 16 + lane16) * 96 + kc);
#pragma unroll
        for (int j = 0; j < 3; ++j)
            bfr[j] = *(const bf16x8*)(kp + (size_t)(wx * 48 + j * 16 + lane16) * 96 + kc);
#pragma unroll
        for (int i = 0; i < 3; ++i)
#pragma unroll
            for (int j = 0; j < 3; ++j)
                acc[i][j] = __builtin_amdgcn_mfma_f32_16x16x32_bf16(af[i], bfr[j], acc[i][j], 0, 0, 0);
    }

    const float scale = 0.0625f;  // 256^-0.5
#pragma unroll
    for (int i = 0; i < 3; ++i) {
        int rbase = wy * 48 + i * 16 + quad * 4;
#pragma unroll
        for (int j = 0; j < 3; ++j) {
            int col = wx * 48 + j * 16 + lane16;
#pragma unroll
            for (int r = 0; r < 4; ++r)
                Ps[(rbase + r) * 104 + col] = __float2bfloat16(acc[i][j][r] * scale);
        }
    }
    __syncthreads();

    // ---- row softmax: 2 threads per row ----
    if (t < 192) {
        int row = t >> 1, hh = t & 1;
        const bf16x4* pr4 = (const bf16x4*)&Ps[row * 104 + hh * 48];
        float vb[48];
        float m = -1e30f;
#pragma unroll
        for (int j4 = 0; j4 < 12; ++j4) {
            bf16x4 u = pr4[j4];
#pragma unroll
            for (int e = 0; e < 4; ++e) {
                float f = bf2f_bits(u[e]);
                vb[j4 * 4 + e] = f;
                m = fmaxf(m, f);
            }
        }
        m = fmaxf(m, __shfl_xor(m, 1));
        float ssum = 0.f;
#pragma unroll
        for (int j2 = 0; j2 < 48; ++j2) { vb[j2] = __expf(vb[j2] - m); ssum += vb[j2]; }
        ssum += __shfl_xor(ssum, 1);
        float inv = 1.f / ssum;
        bf16x4* pw4 = (bf16x4*)&Ps[row * 104 + hh * 48];
#pragma unroll
        for (int j4 = 0; j4 < 12; ++j4) {
            bf16x4 o;
#pragma unroll
            for (int e = 0; e < 4; ++e) o[e] = f2bf_bits(vb[j4 * 4 + e] * inv);
            pw4[j4] = o;
        }
    }
    __syncthreads();

    // ---- PV ----
#pragma unroll
    for (int i = 0; i < 3; ++i)
#pragma unroll
        for (int j = 0; j < 3; ++j) acc[i][j] = (f32x4){0.f, 0.f, 0.f, 0.f};

#pragma unroll
    for (int kb = 0; kb < 3; ++kb) {
        int kc = kb * 32 + quad * 8;
        bf16x8 af[3], bfr[3];
#pragma unroll
        for (int i = 0; i < 3; ++i)
            af[i] = *(const bf16x8*)&Ps[(wy * 48 + i * 16 + lane16) * 104 + kc];
#pragma unroll
        for (int j = 0; j < 3; ++j)
            bfr[j] = *(const bf16x8*)(vp + (size_t)(wx * 48 + j * 16 + lane16) * 96 + kc);
#pragma unroll
        for (int i = 0; i < 3; ++i)
#pragma unroll
            for (int j = 0; j < 3; ++j)
                acc[i][j] = __builtin_amdgcn_mfma_f32_16x16x32_bf16(af[i], bfr[j], acc[i][j], 0, 0, 0);
    }

    __hip_bfloat16* ap = a + ((size_t)(bout0 + b) * CC + (d * 8 + n)) * HW;
#pragma unroll
    for (int i = 0; i < 3; ++i) {
        int rbase = wy * 48 + i * 16 + quad * 4;
#pragma unroll
        for (int j = 0; j < 3; ++j) {
            int col = wx * 48 + j * 16 + lane16;
#pragma unroll
            for (int r = 0; r < 4; ++r)
                ap[(size_t)(rbase + r) * 96 + col] = __float2bfloat16(acc[i][j][r]);
        }
    }
}

// ---------------- fused 3-branch grouped 3x3 conv + exact GELU -> bf16 planar ----------------
__global__ __launch_bounds__(256) void freq3_kernel(const float* __restrict__ x,
                                                    const float* __restrict__ dww,
                                                    const float* __restrict__ dwb,
                                                    __hip_bfloat16* __restrict__ f) {
    int p = blockIdx.x * 256 + threadIdx.x;
    int g = blockIdx.y;
    int b = blockIdx.z;
    int h = p / WW, w = p % WW;
    float a0 = dwb[g], a1 = dwb[64 + g], a2 = dwb[128 + g];
    const float* w0 = dww + g * 36;
    const float* w1 = dww + (64 + g) * 36;
    const float* w2 = dww + (128 + g) * 36;
#pragma unroll
    for (int q = 0; q < 4; ++q) {
        const float* xc = x + ((size_t)b * CC + 4 * g + q) * HW;
#pragma unroll
        for (int dh = 0; dh < 3; ++dh) {
            int hh = h + dh - 1;
            bool hv = (hh >= 0) && (hh < HH);
#pragma unroll
            for (int dw = 0; dw < 3; ++dw) {
                int ww2 = w + dw - 1;
                bool v = hv && (ww2 >= 0) && (ww2 < WW);
                float xv = v ? xc[hh * WW + ww2] : 0.f;
                int wi = q * 9 + dh * 3 + dw;
                a0 += xv * w0[wi];
                a1 += xv * w1[wi];
                a2 += xv * w2[wi];
            }
        }
    }
    a0 = 0.5f * a0 * (1.f + erff(a0 * 0.70710678118654752f));
    a1 = 0.5f * a1 * (1.f + erff(a1 * 0.70710678118654752f));
    a2 = 0.5f * a2 * (1.f + erff(a2 * 0.70710678118654752f));
    size_t base = ((size_t)b * 192 + g) * HW + p;
    f[base] = __float2bfloat16(a0);
    f[base + (size_t)64 * HW] = __float2bfloat16(a1);
    f[base + (size_t)128 * HW] = __float2bfloat16(a2);
}

extern "C" void kernel_launch(void* const* d_in, const int* in_sizes, int n_in,
                              void* d_out, int out_size, void* d_ws, size_t ws_size,
                              hipStream_t stream) {
    const float* x    = (const float*)d_in[0];
    const float* c1w  = (const float*)d_in[1];
    const float* c1b  = (const float*)d_in[2];
    const float* g1   = (const float*)d_in[3];
    const float* be1  = (const float*)d_in[4];
    const float* s1w1 = (const float*)d_in[5];
    const float* s1b1 = (const float*)d_in[6];
    const float* s2w1 = (const float*)d_in[7];
    const float* s2b1 = (const float*)d_in[8];
    const float* c2w  = (const float*)d_in[9];
    const float* c2b  = (const float*)d_in[10];
    const float* g2   = (const float*)d_in[11];
    const float* be2  = (const float*)d_in[12];
    const float* s1w2 = (const float*)d_in[13];
    const float* s1b2 = (const float*)d_in[14];
    const float* s2w2 = (const float*)d_in[15];
    const float* s2b2 = (const float*)d_in[16];
    const float* qkvw = (const float*)d_in[17];
    const float* qkvb = (const float*)d_in[18];
    const float* pjw  = (const float*)d_in[19];
    const float* pjb  = (const float*)d_in[20];
    const float* dww  = (const float*)d_in[21];
    const float* dwb  = (const float*)d_in[22];
    const float* pww  = (const float*)d_in[23];
    const float* pwb  = (const float*)d_in[24];
    const float* fwts = (const float*)d_in[25];
    const float* rw   = (const float*)d_in[26];
    const float* rb   = (const float*)d_in[27];
    float* out = (float*)d_out;
    (void)ws_size;

    char* ws = (char*)d_ws;
    // ---- workspace map (peak ~284.5 MB; >=302.1 MB proven safe) ----
    // [0,151.0M): h2 f32 (phase1); attn phase: qkvs bf16 [0,113.25M) / fall bf16 [0,56.6M)
    float* h2 = (float*)ws;
    __hip_bfloat16* qkvs = (__hip_bfloat16*)ws;                      // 113,246,208 B
    __hip_bfloat16* fall = (__hip_bfloat16*)ws;                      //  56,623,104 B
    // [56.6M, 188.7M): ftA bf16 (B,HW,448) fused proj+freq B matrix (post-attn)
    __hip_bfloat16* ftA = (__hip_bfloat16*)(ws + 56623104ULL);       // 132,120,576 B
    // [113.25M, 151.0M): vt bf16 (8 batches) during attn phase (dead before ftA written)
    __hip_bfloat16* vt = (__hip_bfloat16*)(ws + 113246208ULL);       //  37,748,736 B
    // [151.0M, 188.7M): h1 f32 (phase1)
    float* h1 = (float*)(ws + 150994944ULL);
    // [188.7M, 207.6M): h1t bf16
    __hip_bfloat16* h1t = (__hip_bfloat16*)(ws + 188743680ULL);
    // [207.6M, 283.1M): xt bf16 (B,HW,256); per-half overwritten by at (planar bf16)
    __hip_bfloat16* xt = (__hip_bfloat16*)(ws + 207618048ULL);
    __hip_bfloat16* at = xt;
    // tail [283.1M, ~284.5M): zero page + zeroed accumulators + stats + bf16 weights
    const size_t TB = 283115520ULL;
    short* zp = (short*)(ws + TB);            // 256 B
    float* zf = (float*)(ws + TB + 256);
    float* ssum1  = zf;                       // 1024   (zeroed)
    float* sssq1  = zf + 1024;                // 1024   (zeroed)
    float* ssum2  = zf + 2048;                // 4096   (zeroed)
    float* sssq2  = zf + 6144;                // 4096   (zeroed)
    float* pooled = zf + 10240;               // 4096   (zeroed)  -- end of zero region (14336 f)
    float* route  = zf + 14336;               // 32
    float* fw     = zf + 14368;               // 4
    float* mean1  = zf + 14372;               // 1024
    float* istd1  = zf + 15396;
    float* ag1    = zf + 16420;
    float* ab1    = zf + 17444;
    float* mean2  = zf + 18468;               // 4096
    float* istd2  = zf + 22564;
    float* ag2    = zf + 26660;
    float* ab2    = zf + 30756;
    float* fb448  = zf + 34852;               // 256
    char* wbase = (char*)(zf + 35108);        // 16B-aligned
    __hip_bfloat16* wt1  = (__hip_bfloat16*)wbase;              // 64*9*256  = 294912 B
    __hip_bfloat16* wt2  = (__hip_bfloat16*)(wbase + 294912);   // 256*9*64  = 294912 B
    __hip_bfloat16* qw16 = (__hip_bfloat16*)(wbase + 589824);   // 768*256   = 393216 B
    __hip_bfloat16* A448 = (__hip_bfloat16*)(wbase + 983040);   // 256*448   = 229376 B

    // zero zp + stat accumulators + pooled (64 + 14336 uints)
    zero_n_kernel<<<57, 256, 0, stream>>>((unsigned int*)zp, 14400);

    // x -> pixel-major bf16, fused pooled-sum accumulation
    transpose_pm_kernel<float, 256, 256, true>
        <<<dim3(288, 8, 16), dim3(32, 8), 0, stream>>>(x, xt, pooled);
    router_kernel<<<1, 64, 0, stream>>>(pooled, rw, rb, fwts, route, fw);

    // weight prep
    pack_w3x3_kernel<<<576, 256, 0, stream>>>(c1w, wt1, 64, 256);
    pack_w3x3_kernel<<<576, 256, 0, stream>>>(c2w, wt2, 256, 64);
    cast_w_kernel<<<768, 256, 0, stream>>>(qkvw, qw16, 768 * 256);
    cast_w448_kernel<<<256, 256, 0, stream>>>(pjw, A448);
    fuse_freq_w448_kernel<<<256, 192, 0, stream>>>(pww, pwb, pjb, fw, A448, fb448);

    // branch 1: conv1 (stats fused) -> AFN1+GELU -> conv2 (stats fused) -> fused AFN2+combine
    mfma_gemm_kernel<64, 128, 9, 256, 256, 0, 64, true>
        <<<dim3(1, 72, 16), 256, 0, stream>>>((const short*)wt1, (const short*)xt, zp, c1b,
                                              nullptr, h1, ssum1, sssq1, 0, 0);
    afn_finalize_kernel<<<4, 256, 0, stream>>>(ssum1, sssq1, mean1, istd1, BB * C4);
    afn_mlp_kernel<64, 16><<<dim3(BB), 128, 0, stream>>>(mean1, s1w1, s1b1, s2w1, s2b1, ag1, ab1);
    afn_apply_kernel<64, true><<<dim3(36, 64, 16), 256, 0, stream>>>(h1, mean1, istd1, ag1, ab1, g1, be1);
    transpose_pm_kernel<float, 64, 64, false>
        <<<dim3(288, 2, 16), dim3(32, 8), 0, stream>>>(h1, h1t, nullptr);
    mfma_gemm_kernel<128, 128, 9, 64, 64, 0, 256, true>
        <<<dim3(2, 72, 16), 256, 0, stream>>>((const short*)wt2, (const short*)h1t, zp, c2b,
                                              nullptr, h2, ssum2, sssq2, 0, 0);
    afn_finalize_kernel<<<16, 256, 0, stream>>>(ssum2, sssq2, mean2, istd2, BB * CC);
    afn_mlp_kernel<256, 64><<<dim3(BB), 512, 0, stream>>>(mean2, s1w2, s1b2, s2w2, s2b2, ag2, ab2);
    afn_combine_kernel<<<dim3(9, 256, 16), 256, 0, stream>>>(x, h2, mean2, istd2, ag2, ab2,
                                                             g2, be2, route, out);

    // attention branch, two batch-halves sharing the qkv scratch
    for (int half = 0; half < 2; ++half) {
        mfma_gemm_kernel<128, 128, 1, 256, 256, 1, 768, false>
            <<<dim3(6, 72, 8), 256, 0, stream>>>((const short*)qw16, (const short*)xt, zp, qkvb,
                                                 nullptr, qkvs, nullptr, nullptr, half * 8, 0);
        vtrans_kernel<<<dim3(9, 256, 8), dim3(32, 8), 0, stream>>>(qkvs, vt);
        attn_mfma_kernel<<<dim3(32, 8, 8), 256, 0, stream>>>(qkvs, vt, at, half * 8);
    }

    // frequency branches: all 3 dw convs in one pass over x -> fall (B,192,HW) bf16
    freq3_kernel<<<dim3(36, 64, 16), 256, 0, stream>>>(x, dww, dwb, fall);

    // build fused B matrix ftA[B][HW][448]: cols 0-255 = attn out, 256-447 = freq features
    transpose_pm_kernel<__hip_bfloat16, 256, 448, false>
        <<<dim3(288, 8, 16), dim3(32, 8), 0, stream>>>(at, ftA, nullptr);
    transpose_pm_kernel<__hip_bfloat16, 192, 448, false>
        <<<dim3(288, 6, 16), dim3(32, 8), 0, stream>>>(fall, ftA + 256, nullptr);

    // single fused proj+freq GEMM (K=448): out += route1 * (proj(at) + freq(f) + biases)
    mfma_gemm_kernel<128, 128, 1, 448, 448, 2, 256, false>
        <<<dim3(2, 72, 16), 256, 0, stream>>>((const short*)A448, (const short*)ftA, zp, fb448,
                                              route, out, nullptr, nullptr, 0, 0);
}

// Round 3
// 1223.925 us; speedup vs baseline: 1.3457x; 1.0003x over previous
//
#include <hip/hip_runtime.h>
#include <hip/hip_bf16.h>
#include <math.h>
#include <stdint.h>

#define BB 16
#define CC 256
#define C4 64
#define HH 96
#define WW 96
#define HW 9216
#define EPSF 1e-5f

using bf16x8 = __attribute__((ext_vector_type(8))) short;
using bf16x4 = __attribute__((ext_vector_type(4))) short;
using f32x4  = __attribute__((ext_vector_type(4))) float;

#define GLD16(g, l) \
    __builtin_amdgcn_global_load_lds((const __attribute__((address_space(1))) unsigned int*)(g), \
                                     (__attribute__((address_space(3))) unsigned int*)(l), 16, 0, 0)

__device__ inline float bf2f_bits(short s) {
    return __uint_as_float(((unsigned int)(unsigned short)s) << 16);
}
__device__ inline short f2bf_bits(float f) {
    unsigned int u = __float_as_uint(f);
    return (short)((u + 0x7fffu + ((u >> 16) & 1u)) >> 16);
}

// ---------------- zero init for zp + stat accumulators ----------------
__global__ void zero_n_kernel(unsigned int* __restrict__ p, int n) {
    int i = blockIdx.x * 256 + threadIdx.x;
    if (i < n) p[i] = 0u;
}

// ---------------- router softmax + freq-weight softmax (pooled holds SUMS) ----------------
__global__ void router_kernel(const float* __restrict__ pooled, const float* __restrict__ rw,
                              const float* __restrict__ rb, const float* __restrict__ fwts,
                              float* __restrict__ route, float* __restrict__ fw) {
    int t = threadIdx.x;
    const float invhw = 1.f / (float)HW;
    if (t < BB) {
        float l0 = rb[0], l1 = rb[1];
        for (int c = 0; c < CC; ++c) {
            float p = pooled[t * CC + c] * invhw;
            l0 += p * rw[c];
            l1 += p * rw[CC + c];
        }
        float m = fmaxf(l0, l1);
        float e0 = __expf(l0 - m), e1 = __expf(l1 - m);
        float inv = 1.f / (e0 + e1);
        route[t * 2 + 0] = e0 * inv;
        route[t * 2 + 1] = e1 * inv;
    }
    if (t == BB) {
        float a = fwts[0], b = fwts[1], c = fwts[2];
        float m = fmaxf(a, fmaxf(b, c));
        float e0 = __expf(a - m), e1 = __expf(b - m), e2 = __expf(c - m);
        float inv = 1.f / (e0 + e1 + e2);
        fw[0] = e0 * inv; fw[1] = e1 * inv; fw[2] = e2 * inv;
    }
}

// ---------------- weight prep ----------------
__global__ void pack_w3x3_kernel(const float* __restrict__ w, __hip_bfloat16* __restrict__ wt,
                                 int COUT, int CINW) {
    int idx = blockIdx.x * 256 + threadIdx.x;
    int total = COUT * 9 * CINW;
    if (idx >= total) return;
    int ci = idx % CINW; int rest = idx / CINW; int tau = rest % 9; int co = rest / 9;
    wt[idx] = __float2bfloat16(w[((size_t)co * CINW + ci) * 9 + tau]);
}

__global__ void cast_w_kernel(const float* __restrict__ w, __hip_bfloat16* __restrict__ o, int n) {
    int idx = blockIdx.x * 256 + threadIdx.x;
    if (idx < n) o[idx] = __float2bfloat16(w[idx]);
}

// proj weights (256,256) -> A448 rows [0:256), stride 448
__global__ void cast_w448_kernel(const float* __restrict__ w, __hip_bfloat16* __restrict__ A448) {
    int idx = blockIdx.x * 256 + threadIdx.x;  // 65536
    int co = idx >> 8, ci = idx & 255;
    A448[co * 448 + ci] = __float2bfloat16(w[idx]);
}

// pww (3,256,64)*fw -> A448 cols [256:448); fb448[co] = pjb[co] + sum fw[i]*pwb[i][co]
__global__ void fuse_freq_w448_kernel(const float* __restrict__ pww, const float* __restrict__ pwb,
                                      const float* __restrict__ pjb, const float* __restrict__ fw,
                                      __hip_bfloat16* __restrict__ A448, float* __restrict__ fb448) {
    int co = blockIdx.x; int t = threadIdx.x;  // 192 threads
    int i = t >> 6, g = t & 63;
    A448[co * 448 + 256 + t] = __float2bfloat16(fw[i] * pww[((size_t)(i * 256 + co)) * 64 + g]);
    if (t == 0) fb448[co] = pjb[co] + fw[0] * pwb[co] + fw[1] * pwb[256 + co] + fw[2] * pwb[512 + co];
}

// ---------------- planar (B,CIN,HW) -> pixel-major (B,HW,OSTR) bf16 ----------------
// POOL: accumulate per-(b,c) sums. AFN: apply (v-mean)*scale+shift (+GELU) while transposing.
__device__ inline float to_f32(float v) { return v; }
__device__ inline float to_f32(__hip_bfloat16 v) { return __bfloat162float(v); }

template <typename TIN, int CIN, int OSTR, bool POOL, bool AFN, bool GELU>
__global__ __launch_bounds__(256) void transpose_pm_kernel(const TIN* __restrict__ x,
                                                           __hip_bfloat16* __restrict__ xt,
                                                           float* __restrict__ pooled,
                                                           const float* __restrict__ mean,
                                                           const float* __restrict__ istd,
                                                           const float* __restrict__ ag,
                                                           const float* __restrict__ ab,
                                                           const float* __restrict__ gamma,
                                                           const float* __restrict__ beta) {
    __shared__ float s[32][33];
    __shared__ float ps[8][32];
    int p0 = blockIdx.x * 32, c0 = blockIdx.y * 32, b = blockIdx.z;
    int tx = threadIdx.x, ty = threadIdx.y;  // (32,8)
    const TIN* xp = x + ((size_t)b * CIN + c0) * HW + p0;
#pragma unroll
    for (int i = 0; i < 4; ++i) {
        int c = ty * 4 + i;
        float v = to_f32(xp[(size_t)c * HW + tx]);
        if (AFN) {
            int bc = b * CIN + c0 + c;
            float sc = (1.f + ag[bc]) * gamma[c0 + c] * istd[bc];
            float sh = ab[bc] * beta[c0 + c];
            v = (v - mean[bc]) * sc + sh;
            if (GELU) v = 0.5f * v * (1.f + erff(v * 0.70710678118654752f));
        }
        s[c][tx] = v;
    }
    __syncthreads();
    __hip_bfloat16* yp = xt + ((size_t)b * HW + p0) * OSTR + c0;
#pragma unroll
    for (int i = 0; i < 4; ++i) {
        int r = ty * 4 + i;
        yp[(size_t)r * OSTR + tx] = __float2bfloat16(s[tx][r]);
    }
    if (POOL) {
        float l4 = 0.f;
#pragma unroll
        for (int i = 0; i < 4; ++i) l4 += s[tx][ty * 4 + i];
        ps[ty][tx] = l4;
        __syncthreads();
        if (ty == 0) {
            float tot = 0.f;
#pragma unroll
            for (int k = 0; k < 8; ++k) tot += ps[k][tx];
            atomicAdd(&pooled[b * CIN + c0 + tx], tot);
        }
    }
}

// ---------------- MFMA implicit-GEMM conv ----------------
// Double-buffered BK=64 pipeline: one barrier per stage, next-stage global_load_lds
// issued before MFMA so loads land during compute (T3-min 2-phase).
// LDS chunk-XOR swizzle (lchk ^ ((lrow>>1)&3)) on BOTH stage-source and read side:
// linear gload_lds dest + permuted global src + matching read XOR -> 2-way (free) banks.
// EPI: 0=f32 planar store, 1=bf16 planar store, 2=f32 planar += route[b]*val
// STATS: accumulate per-(b,co) sum / sumsq via atomics (fused channel stats)
template <int BM, int BN, int TSH, int KC, int CDIM, int EPI, int CO_TOT, bool STATS>
__global__ __launch_bounds__(256) void mfma_gemm_kernel(const short* __restrict__ A,
                                                        const short* __restrict__ Bx,
                                                        const short* __restrict__ zp,
                                                        const float* __restrict__ bias,
                                                        const float* __restrict__ route,
                                                        void* __restrict__ Y,
                                                        float* __restrict__ ssum,
                                                        float* __restrict__ sssq,
                                                        int bin0, int bout0) {
    constexpr int WM = BM / 2, WN = BN / 2;
    constexpr int FM = WM / 16, FN = WN / 16;
    constexpr int KBT = KC / 64;       // 64-ch chunks per tap
    constexpr int NS = TSH * KBT;      // total pipeline stages
    constexpr int NA = BM / 16;
    constexpr int NB = BN / 16;
    __shared__ __align__(16) short As[2][2][BM * 32];
    __shared__ __align__(16) short Bs[2][2][BN * 32];
    int tid = threadIdx.x;
    int wid = tid >> 6, lane = tid & 63;
    int wy = wid >> 1, wx = wid & 1;
    int lane16 = lane & 15, quad = lane >> 4;
    int lrow = lane >> 2, lchk = lane & 3;
    int swz = (lrow >> 1) & 3;            // write-side chunk swizzle
    int co0 = blockIdx.x * BM;
    int n0 = blockIdx.y * BN;
    int bin = blockIdx.z + bin0;
    int bout = blockIdx.z + bout0;

    f32x4 acc[FM][FN];
#pragma unroll
    for (int i = 0; i < FM; ++i)
#pragma unroll
        for (int j = 0; j < FN; ++j) acc[i][j] = (f32x4){0.f, 0.f, 0.f, 0.f};

    const short* Bbase = Bx + (size_t)bin * HW * CDIM;

    auto stage = [&](int s, int d) {
        int tau = (TSH > 1) ? (s / KBT) : 0;
        int kb  = s - tau * KBT;
        int kc0 = kb * 64;
        int dh = tau / 3, dw = tau % 3;
        int off = (dh - 1) * 96 + (dw - 1);
        int ksw = kc0 + (lchk ^ swz) * 8;
#pragma unroll
        for (int kk = 0; kk < 2; ++kk) {
#pragma unroll
            for (int t = 0; t < NA / 4; ++t) {
                int inst = wid * (NA / 4) + t;
                int row = inst * 16 + lrow;
                const short* g = A + (size_t)(co0 + row) * (TSH * KC) + tau * KC + ksw + kk * 32;
                GLD16(g, &As[d][kk][inst * 512]);
            }
#pragma unroll
            for (int t = 0; t < NB / 4; ++t) {
                int inst = wid * (NB / 4) + t;
                int row = inst * 16 + lrow;
                int n = n0 + row;
                const short* g;
                if (TSH > 1) {
                    int h = n / 96, w = n - h * 96;
                    int hh = h + dh - 1, ww2 = w + dw - 1;
                    bool valid = ((unsigned)hh < 96u) && ((unsigned)ww2 < 96u);
                    g = valid ? (Bbase + (size_t)(n + off) * CDIM + ksw + kk * 32) : zp;
                } else {
                    g = Bbase + (size_t)n * CDIM + ksw + kk * 32;
                }
                GLD16(g, &Bs[d][kk][inst * 512]);
            }
        }
    };

    stage(0, 0);
    __syncthreads();
    for (int s = 0; s < NS; ++s) {
        int cur = s & 1;
        if (s + 1 < NS) stage(s + 1, cur ^ 1);
#pragma unroll
        for (int kk = 0; kk < 2; ++kk) {
            bf16x8 af[FM], bfr[FN];
#pragma unroll
            for (int i = 0; i < FM; ++i) {
                int row = wy * WM + i * 16 + lane16;
                int ch = (quad ^ ((row >> 1) & 3)) * 8;
                af[i] = *(const bf16x8*)&As[cur][kk][row * 32 + ch];
            }
#pragma unroll
            for (int j = 0; j < FN; ++j) {
                int row = wx * WN + j * 16 + lane16;
                int ch = (quad ^ ((row >> 1) & 3)) * 8;
                bfr[j] = *(const bf16x8*)&Bs[cur][kk][row * 32 + ch];
            }
#pragma unroll
            for (int i = 0; i < FM; ++i)
#pragma unroll
                for (int j = 0; j < FN; ++j)
                    acc[i][j] = __builtin_amdgcn_mfma_f32_16x16x32_bf16(af[i], bfr[j], acc[i][j], 0, 0, 0);
        }
        __syncthreads();
    }

    float scale = 1.f;
    if (EPI == 2) scale = route[bin * 2 + 1];
    float sl[FM][4], ql[FM][4];
    if (STATS) {
#pragma unroll
        for (int i = 0; i < FM; ++i)
#pragma unroll
            for (int r = 0; r < 4; ++r) { sl[i][r] = 0.f; ql[i][r] = 0.f; }
    }
#pragma unroll
    for (int i = 0; i < FM; ++i) {
        int co_l = co0 + wy * WM + i * 16 + quad * 4;
#pragma unroll
        for (int j = 0; j < FN; ++j) {
            int pix = n0 + wx * WN + j * 16 + lane16;
#pragma unroll
            for (int r = 0; r < 4; ++r) {
                int co = co_l + r;
                float v = acc[i][j][r] + bias[co];
                size_t idx = ((size_t)(bout * CO_TOT + co)) * HW + pix;
                if (EPI == 0) ((float*)Y)[idx] = v;
                else if (EPI == 1) ((__hip_bfloat16*)Y)[idx] = __float2bfloat16(v);
                else ((float*)Y)[idx] += scale * v;
                if (STATS) { sl[i][r] += v; ql[i][r] += v * v; }
            }
        }
    }
    if (STATS) {
#pragma unroll
        for (int i = 0; i < FM; ++i) {
            int co_l = co0 + wy * WM + i * 16 + quad * 4;
#pragma unroll
            for (int r = 0; r < 4; ++r) {
                float s = sl[i][r], q = ql[i][r];
                s += __shfl_xor(s, 1); q += __shfl_xor(q, 1);
                s += __shfl_xor(s, 2); q += __shfl_xor(q, 2);
                s += __shfl_xor(s, 4); q += __shfl_xor(q, 4);
                s += __shfl_xor(s, 8); q += __shfl_xor(q, 8);
                if (lane16 == 0) {
                    int bc = bout * CO_TOT + co_l + r;
                    atomicAdd(&ssum[bc], s);
                    atomicAdd(&sssq[bc], q);
                }
            }
        }
    }
}

// ---------------- stats finalize: mean + inv_std (var uses n-1) ----------------
__global__ void afn_finalize_kernel(const float* __restrict__ s, const float* __restrict__ q,
                                    float* __restrict__ mean, float* __restrict__ istd, int n) {
    int i = blockIdx.x * 256 + threadIdx.x;
    if (i >= n) return;
    float m = s[i] / (float)HW;
    float var = (q[i] - s[i] * m) / (float)(HW - 1);
    mean[i] = m;
    istd[i] = rsqrtf(var + EPSF);
}

// ---------------- AFN tiny MLP ----------------
template <int CH, int HID>
__global__ void afn_mlp_kernel(const float* __restrict__ mean,
                               const float* __restrict__ s1w, const float* __restrict__ s1b,
                               const float* __restrict__ s2w, const float* __restrict__ s2b,
                               float* __restrict__ ag, float* __restrict__ ab) {
    int b = blockIdx.x;
    __shared__ float hbuf[HID];
    int t = threadIdx.x;
    if (t < HID) {
        float s = s1b[t];
        for (int c = 0; c < CH; ++c) s += mean[b * CH + c] * s1w[t * CH + c];
        hbuf[t] = fmaxf(s, 0.f);
    }
    __syncthreads();
    if (t < 2 * CH) {
        float s = s2b[t];
#pragma unroll
        for (int k = 0; k < HID; ++k) s += hbuf[k] * s2w[t * HID + k];
        if (t < CH) ag[b * CH + t] = s;
        else        ab[b * CH + (t - CH)] = s;
    }
}

// ---------------- fused AFN2 + combine: out = x + r0*AFN(h2), float4 ----------------
__global__ __launch_bounds__(256) void afn_combine_kernel(const float* __restrict__ x,
                                                          const float* __restrict__ h2,
                                                          const float* __restrict__ mean,
                                                          const float* __restrict__ istd,
                                                          const float* __restrict__ ag,
                                                          const float* __restrict__ ab,
                                                          const float* __restrict__ gamma,
                                                          const float* __restrict__ beta,
                                                          const float* __restrict__ route,
                                                          float* __restrict__ out) {
    int p4 = blockIdx.x * 256 + threadIdx.x;  // float4 index within channel (9216/4 = 2304)
    int c = blockIdx.y, b = blockIdx.z;
    int bc = b * CC + c;
    float scale = (1.f + ag[bc]) * gamma[c] * istd[bc];
    float shift = ab[bc] * beta[c];
    float m = mean[bc];
    float r0 = route[b * 2];
    size_t base = (size_t)bc * (HW / 4) + p4;
    const f32x4 xv = ((const f32x4*)x)[base];
    const f32x4 hv = ((const f32x4*)h2)[base];
    f32x4 o;
#pragma unroll
    for (int e = 0; e < 4; ++e) o[e] = xv[e] + r0 * ((hv[e] - m) * scale + shift);
    ((f32x4*)out)[base] = o;
}

// ---------------- spatial transpose of V channels: [g][w] -> [w][g] bf16 ----------------
__global__ __launch_bounds__(256) void vtrans_kernel(const __hip_bfloat16* __restrict__ qkv,
                                                     __hip_bfloat16* __restrict__ vt) {
    __shared__ __hip_bfloat16 s[32][34];
    int th = blockIdx.x / 3, tw = blockIdx.x % 3;   // 3x3 tiles of 32
    int c = blockIdx.y, b = blockIdx.z;
    int tx = threadIdx.x, ty = threadIdx.y;  // (32,8)
    const __hip_bfloat16* ip = qkv + ((size_t)b * 768 + 512 + c) * HW + (size_t)(th * 32) * 96 + tw * 32;
#pragma unroll
    for (int i = 0; i < 4; ++i) s[ty * 4 + i][tx] = ip[(size_t)(ty * 4 + i) * 96 + tx];
    __syncthreads();
    __hip_bfloat16* op = vt + ((size_t)b * 256 + c) * HW + (size_t)(tw * 32) * 96 + th * 32;
#pragma unroll
    for (int i = 0; i < 4; ++i) op[(size_t)(ty * 4 + i) * 96 + tx] = s[tx][ty * 4 + i];
}

// ---------------- MFMA attention: one block per (d, n, b_local) ----------------
__global__ __launch_bounds__(256) void attn_mfma_kernel(const __hip_bfloat16* __restrict__ qkv,
                                                        const __hip_bfloat16* __restrict__ vt,
                                                        __hip_bfloat16* __restrict__ a, int bout0) {
    int d = blockIdx.x, n = blockIdx.y, b = blockIdx.z;
    __shared__ __align__(16) __hip_bfloat16 Ps[96 * 104];
    int t = threadIdx.x;
    int lane = t & 63, wid = t >> 6;
    int wy = wid >> 1, wx = wid & 1;
    int lane16 = lane & 15, quad = lane >> 4;

    const __hip_bfloat16* qp = qkv + ((size_t)b * 768 + n * 32 + d) * HW;
    const __hip_bfloat16* kp = qp + (size_t)256 * HW;
    const __hip_bfloat16* vp = vt + ((size_t)b * 256 + n * 32 + d) * HW;

    f32x4 acc[3][3];
#pragma unroll
    for (int i = 0; i < 3; ++i)
#pragma unroll
        for (int j = 0; j < 3; ++j) acc[i][j] = (f32x4){0.f, 0.f, 0.f, 0.f};

    // ---- QK^T ----
#pragma unroll
    for (int kb = 0; kb < 3; ++kb) {
        int kc = kb * 32 + quad * 8;
        bf16x8 af[3], bfr[3];
#pragma unroll
        for (int i = 0; i < 3; ++i)
            af[i] = *(const bf16x8*)(qp + (size_t)(wy * 48 + i * 16 + lane16) * 96 + kc);
#pragma unroll
        for (int j = 0; j < 3; ++j)
            bfr[j] = *(const bf16x8*)(kp + (size_t)(wx * 48 + j * 16 + lane16) * 96 + kc);
#pragma unroll
        for (int i = 0; i < 3; ++i)
#pragma unroll
            for (int j = 0; j < 3; ++j)
                acc[i][j] = __builtin_amdgcn_mfma_f32_16x16x32_bf16(af[i], bfr[j], acc[i][j], 0, 0, 0);
    }

    const float scale = 0.0625f;  // 256^-0.5
#pragma unroll
    for (int i = 0; i < 3; ++i) {
        int rbase = wy * 48 + i * 16 + quad * 4;
#pragma unroll
        for (int j = 0; j < 3; ++j) {
            int col = wx * 48 + j * 16 + lane16;
#pragma unroll
            for (int r = 0; r < 4; ++r)
                Ps[(rbase + r) * 104 + col] = __float2bfloat16(acc[i][j][r] * scale);
        }
    }
    __syncthreads();

    // ---- row softmax: 2 threads per row ----
    if (t < 192) {
        int row = t >> 1, hh = t & 1;
        const bf16x4* pr4 = (const bf16x4*)&Ps[row * 104 + hh * 48];
        float vb[48];
        float m = -1e30f;
#pragma unroll
        for (int j4 = 0; j4 < 12; ++j4) {
            bf16x4 u = pr4[j4];
#pragma unroll
            for (int e = 0; e < 4; ++e) {
                float f = bf2f_bits(u[e]);
                vb[j4 * 4 + e] = f;
                m = fmaxf(m, f);
            }
        }
        m = fmaxf(m, __shfl_xor(m, 1));
        float ssum = 0.f;
#pragma unroll
        for (int j2 = 0; j2 < 48; ++j2) { vb[j2] = __expf(vb[j2] - m); ssum += vb[j2]; }
        ssum += __shfl_xor(ssum, 1);
        float inv = 1.f / ssum;
        bf16x4* pw4 = (bf16x4*)&Ps[row * 104 + hh * 48];
#pragma unroll
        for (int j4 = 0; j4 < 12; ++j4) {
            bf16x4 o;
#pragma unroll
            for (int e = 0; e < 4; ++e) o[e] = f2bf_bits(vb[j4 * 4 + e] * inv);
            pw4[j4] = o;
        }
    }
    __syncthreads();

    // ---- PV ----
#pragma unroll
    for (int i = 0; i < 3; ++i)
#pragma unroll
        for (int j = 0; j < 3; ++j) acc[i][j] = (f32x4){0.f, 0.f, 0.f, 0.f};

#pragma unroll
    for (int kb = 0; kb < 3; ++kb) {
        int kc = kb * 32 + quad * 8;
        bf16x8 af[3], bfr[3];
#pragma unroll
        for (int i = 0; i < 3; ++i)
            af[i] = *(const bf16x8*)&Ps[(wy * 48 + i * 16 + lane16) * 104 + kc];
#pragma unroll
        for (int j = 0; j < 3; ++j)
            bfr[j] = *(const bf16x8*)(vp + (size_t)(wx * 48 + j * 16 + lane16) * 96 + kc);
#pragma unroll
        for (int i = 0; i < 3; ++i)
#pragma unroll
            for (int j = 0; j < 3; ++j)
                acc[i][j] = __builtin_amdgcn_mfma_f32_16x16x32_bf16(af[i], bfr[j], acc[i][j], 0, 0, 0);
    }

    __hip_bfloat16* ap = a + ((size_t)(bout0 + b) * CC + (d * 8 + n)) * HW;
#pragma unroll
    for (int i = 0; i < 3; ++i) {
        int rbase = wy * 48 + i * 16 + quad * 4;
#pragma unroll
        for (int j = 0; j < 3; ++j) {
            int col = wx * 48 + j * 16 + lane16;
#pragma unroll
            for (int r = 0; r < 4; ++r)
                ap[(size_t)(rbase + r) * 96 + col] = __float2bfloat16(acc[i][j][r]);
        }
    }
}

// ---------------- fused 3-branch grouped 3x3 conv + exact GELU -> bf16 planar ----------------
__global__ __launch_bounds__(256) void freq3_kernel(const float* __restrict__ x,
                                                    const float* __restrict__ dww,
                                                    const float* __restrict__ dwb,
                                                    __hip_bfloat16* __restrict__ f) {
    int p = blockIdx.x * 256 + threadIdx.x;
    int g = blockIdx.y;
    int b = blockIdx.z;
    int h = p / WW, w = p % WW;
    float a0 = dwb[g], a1 = dwb[64 + g], a2 = dwb[128 + g];
    const float* w0 = dww + g * 36;
    const float* w1 = dww + (64 + g) * 36;
    const float* w2 = dww + (128 + g) * 36;
#pragma unroll
    for (int q = 0; q < 4; ++q) {
        const float* xc = x + ((size_t)b * CC + 4 * g + q) * HW;
#pragma unroll
        for (int dh = 0; dh < 3; ++dh) {
            int hh = h + dh - 1;
            bool hv = (hh >= 0) && (hh < HH);
#pragma unroll
            for (int dw = 0; dw < 3; ++dw) {
                int ww2 = w + dw - 1;
                bool v = hv && (ww2 >= 0) && (ww2 < WW);
                float xv = v ? xc[hh * WW + ww2] : 0.f;
                int wi = q * 9 + dh * 3 + dw;
                a0 += xv * w0[wi];
                a1 += xv * w1[wi];
                a2 += xv * w2[wi];
            }
        }
    }
    a0 = 0.5f * a0 * (1.f + erff(a0 * 0.70710678118654752f));
    a1 = 0.5f * a1 * (1.f + erff(a1 * 0.70710678118654752f));
    a2 = 0.5f * a2 * (1.f + erff(a2 * 0.70710678118654752f));
    size_t base = ((size_t)b * 192 + g) * HW + p;
    f[base] = __float2bfloat16(a0);
    f[base + (size_t)64 * HW] = __float2bfloat16(a1);
    f[base + (size_t)128 * HW] = __float2bfloat16(a2);
}

extern "C" void kernel_launch(void* const* d_in, const int* in_sizes, int n_in,
                              void* d_out, int out_size, void* d_ws, size_t ws_size,
                              hipStream_t stream) {
    const float* x    = (const float*)d_in[0];
    const float* c1w  = (const float*)d_in[1];
    const float* c1b  = (const float*)d_in[2];
    const float* g1   = (const float*)d_in[3];
    const float* be1  = (const float*)d_in[4];
    const float* s1w1 = (const float*)d_in[5];
    const float* s1b1 = (const float*)d_in[6];
    const float* s2w1 = (const float*)d_in[7];
    const float* s2b1 = (const float*)d_in[8];
    const float* c2w  = (const float*)d_in[9];
    const float* c2b  = (const float*)d_in[10];
    const float* g2   = (const float*)d_in[11];
    const float* be2  = (const float*)d_in[12];
    const float* s1w2 = (const float*)d_in[13];
    const float* s1b2 = (const float*)d_in[14];
    const float* s2w2 = (const float*)d_in[15];
    const float* s2b2 = (const float*)d_in[16];
    const float* qkvw = (const float*)d_in[17];
    const float* qkvb = (const float*)d_in[18];
    const float* pjw  = (const float*)d_in[19];
    const float* pjb  = (const float*)d_in[20];
    const float* dww  = (const float*)d_in[21];
    const float* dwb  = (const float*)d_in[22];
    const float* pww  = (const float*)d_in[23];
    const float* pwb  = (const float*)d_in[24];
    const float* fwts = (const float*)d_in[25];
    const float* rw   = (const float*)d_in[26];
    const float* rb   = (const float*)d_in[27];
    float* out = (float*)d_out;
    (void)ws_size;

    char* ws = (char*)d_ws;
    // ---- workspace map (peak ~284.5 MB; >=302.1 MB proven safe) ----
    float* h2 = (float*)ws;
    __hip_bfloat16* qkvs = (__hip_bfloat16*)ws;                      // 113,246,208 B
    __hip_bfloat16* fall = (__hip_bfloat16*)ws;                      //  56,623,104 B
    __hip_bfloat16* ftA = (__hip_bfloat16*)(ws + 56623104ULL);       // 132,120,576 B
    __hip_bfloat16* vt = (__hip_bfloat16*)(ws + 113246208ULL);       //  37,748,736 B
    float* h1 = (float*)(ws + 150994944ULL);
    __hip_bfloat16* h1t = (__hip_bfloat16*)(ws + 188743680ULL);
    __hip_bfloat16* xt = (__hip_bfloat16*)(ws + 207618048ULL);
    __hip_bfloat16* at = xt;
    const size_t TB = 283115520ULL;
    short* zp = (short*)(ws + TB);            // 256 B
    float* zf = (float*)(ws + TB + 256);
    float* ssum1  = zf;                       // 1024   (zeroed)
    float* sssq1  = zf + 1024;                // 1024   (zeroed)
    float* ssum2  = zf + 2048;                // 4096   (zeroed)
    float* sssq2  = zf + 6144;                // 4096   (zeroed)
    float* pooled = zf + 10240;               // 4096   (zeroed)  -- end of zero region (14336 f)
    float* route  = zf + 14336;               // 32
    float* fw     = zf + 14368;               // 4
    float* mean1  = zf + 14372;               // 1024
    float* istd1  = zf + 15396;
    float* ag1    = zf + 16420;
    float* ab1    = zf + 17444;
    float* mean2  = zf + 18468;               // 4096
    float* istd2  = zf + 22564;
    float* ag2    = zf + 26660;
    float* ab2    = zf + 30756;
    float* fb448  = zf + 34852;               // 256
    char* wbase = (char*)(zf + 35108);        // 16B-aligned
    __hip_bfloat16* wt1  = (__hip_bfloat16*)wbase;              // 64*9*256  = 294912 B
    __hip_bfloat16* wt2  = (__hip_bfloat16*)(wbase + 294912);   // 256*9*64  = 294912 B
    __hip_bfloat16* qw16 = (__hip_bfloat16*)(wbase + 589824);   // 768*256   = 393216 B
    __hip_bfloat16* A448 = (__hip_bfloat16*)(wbase + 983040);   // 256*448   = 229376 B

    // zero zp + stat accumulators + pooled (64 + 14336 uints)
    zero_n_kernel<<<57, 256, 0, stream>>>((unsigned int*)zp, 14400);

    // x -> pixel-major bf16, fused pooled-sum accumulation
    transpose_pm_kernel<float, 256, 256, true, false, false>
        <<<dim3(288, 8, 16), dim3(32, 8), 0, stream>>>(x, xt, pooled, nullptr, nullptr,
                                                       nullptr, nullptr, nullptr, nullptr);
    router_kernel<<<1, 64, 0, stream>>>(pooled, rw, rb, fwts, route, fw);

    // weight prep
    pack_w3x3_kernel<<<576, 256, 0, stream>>>(c1w, wt1, 64, 256);
    pack_w3x3_kernel<<<576, 256, 0, stream>>>(c2w, wt2, 256, 64);
    cast_w_kernel<<<768, 256, 0, stream>>>(qkvw, qw16, 768 * 256);
    cast_w448_kernel<<<256, 256, 0, stream>>>(pjw, A448);
    fuse_freq_w448_kernel<<<256, 192, 0, stream>>>(pww, pwb, pjb, fw, A448, fb448);

    // branch 1: conv1 (stats fused) -> AFN1+GELU fused into transpose -> conv2 (stats fused)
    mfma_gemm_kernel<64, 128, 9, 256, 256, 0, 64, true>
        <<<dim3(1, 72, 16), 256, 0, stream>>>((const short*)wt1, (const short*)xt, zp, c1b,
                                              nullptr, h1, ssum1, sssq1, 0, 0);
    afn_finalize_kernel<<<4, 256, 0, stream>>>(ssum1, sssq1, mean1, istd1, BB * C4);
    afn_mlp_kernel<64, 16><<<dim3(BB), 128, 0, stream>>>(mean1, s1w1, s1b1, s2w1, s2b1, ag1, ab1);
    transpose_pm_kernel<float, 64, 64, false, true, true>
        <<<dim3(288, 2, 16), dim3(32, 8), 0, stream>>>(h1, h1t, nullptr, mean1, istd1,
                                                       ag1, ab1, g1, be1);
    mfma_gemm_kernel<128, 128, 9, 64, 64, 0, 256, true>
        <<<dim3(2, 72, 16), 256, 0, stream>>>((const short*)wt2, (const short*)h1t, zp, c2b,
                                              nullptr, h2, ssum2, sssq2, 0, 0);
    afn_finalize_kernel<<<16, 256, 0, stream>>>(ssum2, sssq2, mean2, istd2, BB * CC);
    afn_mlp_kernel<256, 64><<<dim3(BB), 512, 0, stream>>>(mean2, s1w2, s1b2, s2w2, s2b2, ag2, ab2);
    afn_combine_kernel<<<dim3(9, 256, 16), 256, 0, stream>>>(x, h2, mean2, istd2, ag2, ab2,
                                                             g2, be2, route, out);

    // attention branch, two batch-halves sharing the qkv scratch
    for (int half = 0; half < 2; ++half) {
        mfma_gemm_kernel<128, 128, 1, 256, 256, 1, 768, false>
            <<<dim3(6, 72, 8), 256, 0, stream>>>((const short*)qw16, (const short*)xt, zp, qkvb,
                                                 nullptr, qkvs, nullptr, nullptr, half * 8, 0);
        vtrans_kernel<<<dim3(9, 256, 8), dim3(32, 8), 0, stream>>>(qkvs, vt);
        attn_mfma_kernel<<<dim3(32, 8, 8), 256, 0, stream>>>(qkvs, vt, at, half * 8);
    }

    // frequency branches: all 3 dw convs in one pass over x -> fall (B,192,HW) bf16
    freq3_kernel<<<dim3(36, 64, 16), 256, 0, stream>>>(x, dww, dwb, fall);

    // build fused B matrix ftA[B][HW][448]: cols 0-255 = attn out, 256-447 = freq features
    transpose_pm_kernel<__hip_bfloat16, 256, 448, false, false, false>
        <<<dim3(288, 8, 16), dim3(32, 8), 0, stream>>>(at, ftA, nullptr, nullptr, nullptr,
                                                       nullptr, nullptr, nullptr, nullptr);
    transpose_pm_kernel<__hip_bfloat16, 192, 448, false, false, false>
        <<<dim3(288, 6, 16), dim3(32, 8), 0, stream>>>(fall, ftA + 256, nullptr, nullptr, nullptr,
                                                       nullptr, nullptr, nullptr, nullptr);

    // single fused proj+freq GEMM (K=448): out += route1 * (proj(at) + freq(f) + biases)
    mfma_gemm_kernel<128, 128, 1, 448, 448, 2, 256, false>
        <<<dim3(2, 72, 16), 256, 0, stream>>>((const short*)A448, (const short*)ftA, zp, fb448,
                                              route, out, nullptr, nullptr, 0, 0);
}